// Round 1
// baseline (1116.473 us; speedup 1.0000x reference)
//
#include <hip/hip_runtime.h>

#define KK 3
#define N_ 8
#define C_ 64
#define H_ 128
#define W_ 512
#define CO_ 64
#define HW_ (H_*W_)
#define NTAP 9
#define OFFCH 18

// ---------------------------------------------------------------------------
// Kernel W: transpose w_def [co][c][3][3] -> wT[t][c][co]  (147456 floats? no:
// 9*64*64 = 36864 floats = 147456 B). Destination-major; src reads stride-9
// but total data is tiny and L2-resident.
// ---------------------------------------------------------------------------
__global__ void k_transpose_w(const float* __restrict__ w_def,
                              float* __restrict__ wT) {
    int idx = blockIdx.x * 256 + threadIdx.x;   // 36864 total
    if (idx >= NTAP * C_ * CO_) return;
    int t  = idx / (C_ * CO_);
    int r  = idx % (C_ * CO_);
    int c  = r / CO_;
    int co = r % CO_;
    wT[idx] = w_def[(co * C_ + c) * NTAP + t];
}

// ---------------------------------------------------------------------------
// Kernel 1: offset conv (plain 3x3, 18 out channels), NCHW direct.
// One block = one (n,y) row of 512 px; thread handles x=tid and x=tid+256.
// w_off staged in LDS as [dydx][c][20] (pad to 20 for 16B-aligned float4).
// Output: off_ws[pix][18] pixel-major.
// ---------------------------------------------------------------------------
__global__ __launch_bounds__(256) void k_offsets(
        const float* __restrict__ x,
        const float* __restrict__ w_off,
        const float* __restrict__ b_off,
        float* __restrict__ off_ws) {
    __shared__ float ldsW[NTAP * C_ * 20];   // 46080 B
    int tid = threadIdx.x;

    for (int s = tid; s < OFFCH * C_ * NTAP; s += 256) {
        int t    = s / (C_ * NTAP);       // w_off flat = t*576 + c*9 + dydx
        int rem  = s % (C_ * NTAP);
        int c    = rem / NTAP;
        int dydx = rem % NTAP;
        ldsW[(dydx * C_ + c) * 20 + t] = w_off[s];
    }
    __syncthreads();

    int row = blockIdx.x;          // n*H + y
    int n = row / H_;
    int y = row % H_;
    int xA = tid;                  // xB = xA + 256

    float accA[OFFCH], accB[OFFCH];
    #pragma unroll
    for (int t = 0; t < OFFCH; t++) {
        float bv = b_off[t];
        accA[t] = bv; accB[t] = bv;
    }

    const float* xn = x + (size_t)n * C_ * HW_;
    for (int c = 0; c < C_; c++) {
        const float* xc = xn + c * HW_;
        #pragma unroll
        for (int dydx = 0; dydx < 9; dydx++) {
            int dy = dydx / 3, dx = dydx % 3;
            int yy = y + dy - 1;
            bool rowok = (yy >= 0) && (yy < H_);
            int xxA = xA + dx - 1;
            int xxB = xxA + 256;
            float vA = (rowok && xxA >= 0 && xxA < W_) ? xc[yy * W_ + xxA] : 0.f;
            float vB = (rowok && xxB < W_)             ? xc[yy * W_ + xxB] : 0.f;

            const float* wp = &ldsW[(dydx * C_ + c) * 20];
            float wv[20];
            *(float4*)&wv[0]  = *(const float4*)&wp[0];
            *(float4*)&wv[4]  = *(const float4*)&wp[4];
            *(float4*)&wv[8]  = *(const float4*)&wp[8];
            *(float4*)&wv[12] = *(const float4*)&wp[12];
            *(float2*)&wv[16] = *(const float2*)&wp[16];
            #pragma unroll
            for (int t = 0; t < OFFCH; t++) {
                accA[t] = fmaf(vA, wv[t], accA[t]);
                accB[t] = fmaf(vB, wv[t], accB[t]);
            }
        }
    }

    int pixA = row * W_ + xA;
    float* oA = off_ws + (size_t)pixA * OFFCH;
    float* oB = oA + 256 * OFFCH;
    #pragma unroll
    for (int t = 0; t < OFFCH; t++) { oA[t] = accA[t]; oB[t] = accB[t]; }
}

// ---------------------------------------------------------------------------
// Bilinear metadata: 4 weights (validity folded in) + 4 clamped linear offsets
// ---------------------------------------------------------------------------
__device__ __forceinline__ void bilin_meta(float py, float px,
        float& w00, float& w01, float& w10, float& w11,
        int& o00, int& o01, int& o10, int& o11) {
    float fy0 = floorf(py), fx0 = floorf(px);
    int iy0 = (int)fy0, ix0 = (int)fx0;
    int iy1 = iy0 + 1,  ix1 = ix0 + 1;
    float ly = py - fy0, lx = px - fx0;
    float hy = 1.f - ly, hx = 1.f - lx;
    bool y0ok = (iy0 >= 0) && (iy0 < H_);
    bool y1ok = (iy1 >= 0) && (iy1 < H_);
    bool x0ok = (ix0 >= 0) && (ix0 < W_);
    bool x1ok = (ix1 >= 0) && (ix1 < W_);
    w00 = hy * hx * ((y0ok && x0ok) ? 1.f : 0.f);
    w01 = hy * lx * ((y0ok && x1ok) ? 1.f : 0.f);
    w10 = ly * hx * ((y1ok && x0ok) ? 1.f : 0.f);
    w11 = ly * lx * ((y1ok && x1ok) ? 1.f : 0.f);
    int y0c = min(max(iy0, 0), H_ - 1), y1c = min(max(iy1, 0), H_ - 1);
    int x0c = min(max(ix0, 0), W_ - 1), x1c = min(max(ix1, 0), W_ - 1);
    o00 = y0c * W_ + x0c; o01 = y0c * W_ + x1c;
    o10 = y1c * W_ + x0c; o11 = y1c * W_ + x1c;
}

// ---------------------------------------------------------------------------
// Kernel 2: deformable conv. One block = one (n,y) row; thread handles
// pixels x=tid and x=tid+256, all 64 output channels in registers.
// Per tap: stage wT[t] (16 KB) to LDS, compute bilinear meta, then c-loop:
// 8 near-coalesced gathers + 16 broadcast ds_read_b128 + 128 FMAs.
// ---------------------------------------------------------------------------
__global__ __launch_bounds__(256) void k_deform(
        const float* __restrict__ x,
        const float* __restrict__ off_ws,
        const float* __restrict__ wT,
        const float* __restrict__ b_def,
        float* __restrict__ out) {
    __shared__ float ldsW[C_ * CO_];   // 16 KB (current tap)
    int tid = threadIdx.x;
    int row = blockIdx.x;              // n*H + y
    int n = row / H_;
    int y = row % H_;
    int xA = tid;
    int xB = tid + 256;

    float4 accA[16], accB[16];
    #pragma unroll
    for (int k = 0; k < 16; k++) {
        accA[k] = make_float4(0.f, 0.f, 0.f, 0.f);
        accB[k] = make_float4(0.f, 0.f, 0.f, 0.f);
    }

    const float* xn = x + (size_t)n * C_ * HW_;
    int pixA = row * W_ + xA;
    const float* offA = off_ws + (size_t)pixA * OFFCH;
    const float* offB = offA + 256 * OFFCH;

    for (int t = 0; t < NTAP; t++) {
        __syncthreads();   // protect ldsW from previous tap's readers
        for (int s = tid; s < C_ * CO_; s += 256)
            ldsW[s] = wT[t * C_ * CO_ + s];
        __syncthreads();

        int i = t / 3, j = t % 3;
        float pyA = (float)(y - 1 + i)  + offA[2 * t];
        float pxA = (float)(xA - 1 + j) + offA[2 * t + 1];
        float pyB = (float)(y - 1 + i)  + offB[2 * t];
        float pxB = (float)(xB - 1 + j) + offB[2 * t + 1];

        float w00A, w01A, w10A, w11A, w00B, w01B, w10B, w11B;
        int o00A, o01A, o10A, o11A, o00B, o01B, o10B, o11B;
        bilin_meta(pyA, pxA, w00A, w01A, w10A, w11A, o00A, o01A, o10A, o11A);
        bilin_meta(pyB, pxB, w00B, w01B, w10B, w11B, o00B, o01B, o10B, o11B);

        const float* xc = xn;
        for (int c = 0; c < C_; c++, xc += HW_) {
            float sA = w00A * xc[o00A];
            sA = fmaf(w01A, xc[o01A], sA);
            sA = fmaf(w10A, xc[o10A], sA);
            sA = fmaf(w11A, xc[o11A], sA);
            float sB = w00B * xc[o00B];
            sB = fmaf(w01B, xc[o01B], sB);
            sB = fmaf(w10B, xc[o10B], sB);
            sB = fmaf(w11B, xc[o11B], sB);

            const float4* wr = (const float4*)&ldsW[c * CO_];
            #pragma unroll
            for (int k = 0; k < 16; k++) {
                float4 wv = wr[k];
                float4 a = accA[k];
                a.x = fmaf(wv.x, sA, a.x);
                a.y = fmaf(wv.y, sA, a.y);
                a.z = fmaf(wv.z, sA, a.z);
                a.w = fmaf(wv.w, sA, a.w);
                accA[k] = a;
                float4 b = accB[k];
                b.x = fmaf(wv.x, sB, b.x);
                b.y = fmaf(wv.y, sB, b.y);
                b.z = fmaf(wv.z, sB, b.z);
                b.w = fmaf(wv.w, sB, b.w);
                accB[k] = b;
            }
        }
    }

    // epilogue: out[n][co][y][x] = acc + b_def[co]; lanes along x -> coalesced
    #pragma unroll
    for (int k = 0; k < 16; k++) {
        #pragma unroll
        for (int e = 0; e < 4; e++) {
            int co = k * 4 + e;
            float bv = b_def[co];
            float av = (e == 0) ? accA[k].x : (e == 1) ? accA[k].y
                     : (e == 2) ? accA[k].z : accA[k].w;
            float bvv = (e == 0) ? accB[k].x : (e == 1) ? accB[k].y
                      : (e == 2) ? accB[k].z : accB[k].w;
            size_t base = ((size_t)(n * CO_ + co) * H_ + y) * W_;
            out[base + xA] = av + bv;
            out[base + xB] = bvv + bv;
        }
    }
}

// ---------------------------------------------------------------------------
extern "C" void kernel_launch(void* const* d_in, const int* in_sizes, int n_in,
                              void* d_out, int out_size, void* d_ws, size_t ws_size,
                              hipStream_t stream) {
    const float* x     = (const float*)d_in[0];
    const float* w_off = (const float*)d_in[1];
    const float* b_off = (const float*)d_in[2];
    const float* w_def = (const float*)d_in[3];
    const float* b_def = (const float*)d_in[4];
    float* out = (float*)d_out;

    // ws layout: wT (147456 B) at 0; off_ws (37.75 MB) at 256 KiB.
    float* wT     = (float*)d_ws;
    float* off_ws = (float*)((char*)d_ws + (256 * 1024));

    hipLaunchKernelGGL(k_transpose_w, dim3(144), dim3(256), 0, stream, w_def, wT);
    hipLaunchKernelGGL(k_offsets, dim3(N_ * H_), dim3(256), 0, stream,
                       x, w_off, b_off, off_ws);
    hipLaunchKernelGGL(k_deform, dim3(N_ * H_), dim3(256), 0, stream,
                       x, off_ws, wT, b_def, out);
}

// Round 2
// 1062.853 us; speedup vs baseline: 1.0504x; 1.0504x over previous
//
#include <hip/hip_runtime.h>

#define N_ 8
#define C_ 64
#define H_ 128
#define W_ 512
#define CO_ 64
#define HW_ (H_*W_)
#define NTAP 9

typedef short s8v __attribute__((ext_vector_type(8)));   // 8 bf16 in 4 VGPRs
typedef float f16v __attribute__((ext_vector_type(16))); // 32x32 acc

__device__ __forceinline__ unsigned short f2bf(float f) {
    unsigned u = __float_as_uint(f);
    u += 0x7FFF + ((u >> 16) & 1u);     // round-to-nearest-even
    return (unsigned short)(u >> 16);
}
__device__ __forceinline__ unsigned packbf(float a, float b) {
    return (unsigned)f2bf(a) | ((unsigned)f2bf(b) << 16);
}

// ---------------------------------------------------------------------------
// Prep: w_def [co][c][3][3] -> wTb bf16 [t][co][c]  (B-operand: k=c contiguous)
//       w_off [18][c][3][3] -> wOb bf16 [t][32][c]  (och padded 18->32 w/ 0)
// ---------------------------------------------------------------------------
__global__ void k_prep_w(const float* __restrict__ w_def,
                         const float* __restrict__ w_off,
                         unsigned short* __restrict__ wTb,
                         unsigned short* __restrict__ wOb) {
    int idx = blockIdx.x * 256 + threadIdx.x;
    if (idx < NTAP * CO_ * C_) {
        int t = idx / (CO_ * C_);
        int r = idx % (CO_ * C_);
        int co = r / C_, c = r % C_;
        wTb[idx] = f2bf(w_def[(co * C_ + c) * NTAP + t]);
    }
    if (idx < NTAP * 32 * C_) {
        int t = idx / (32 * C_);
        int r = idx % (32 * C_);
        int oc = r / C_, c = r % C_;
        float v = (oc < 18) ? w_off[(oc * C_ + c) * NTAP + t] : 0.f;
        wOb[idx] = f2bf(v);
    }
}

// ---------------------------------------------------------------------------
// Offset conv as MFMA GEMM: M=128px/block, K=576 (9 taps x 64c), N=32 (18 used)
// Block b: xcd=b&7 -> n (8 images = 8 XCDs), lidx=b>>3 -> (y, x-chunk): keeps
// consecutive rows co-resident per XCD for L2 reuse of x.
// ---------------------------------------------------------------------------
__global__ __launch_bounds__(256, 4) void k_off_mfma(
        const float* __restrict__ x,
        const unsigned short* __restrict__ wOb,
        const float* __restrict__ b_off,
        float* __restrict__ off_ws) {
    __shared__ __align__(16) char smem[21760];
    char* Bo = smem;              // [32][68] bf16 = 4352 B
    char* S  = smem + 4352;       // [128][68] bf16 = 17408 B
    float* E = (float*)smem;      // [128][33] f32 = 16896 B (epilogue reuse)

    int tid = threadIdx.x;
    int b = blockIdx.x;
    int n = b & 7;
    int lidx = b >> 3;
    int y = lidx >> 2;
    int xb = (lidx & 3) << 7;
    int lane = tid & 63, wave = tid >> 6;
    int p = tid & 127, cg = tid >> 7;

    f16v acc;
    #pragma unroll
    for (int r = 0; r < 16; r++) acc[r] = 0.f;

    const float* xn = x + (size_t)n * C_ * HW_;

    for (int t = 0; t < NTAP; t++) {
        int yy = y + (t / 3) - 1;
        if (yy < 0 || yy >= H_) continue;   // block-uniform
        __syncthreads();
        // stage Bo (1024 u32)
        {
            const unsigned* src = (const unsigned*)(wOb + t * 32 * C_);
            #pragma unroll
            for (int k = 0; k < 4; k++) {
                int s = tid + k * 256;
                int co = s >> 5, q = s & 31;
                *(unsigned*)(Bo + co * 136 + q * 4) = src[s];
            }
        }
        // sample S: plain shifted read, zero OOB; lanes along x -> coalesced
        {
            int xx = xb + p + (t % 3) - 1;
            bool ok = (xx >= 0) && (xx < W_);
            const float* xr = xn + (size_t)(cg * 32) * HW_ + yy * W_;
            char* sp = S + p * 136 + (cg * 32) * 2;
            #pragma unroll 4
            for (int u = 0; u < 16; u++) {
                float v0 = ok ? xr[xx] : 0.f;
                float v1 = ok ? xr[HW_ + xx] : 0.f;
                *(unsigned*)sp = packbf(v0, v1);
                sp += 4;
                xr += 2 * HW_;
            }
        }
        __syncthreads();
        // MFMA: wave w -> px block w*32; och 0..31
        {
            int la = lane & 31, kh = lane >> 5;
            const char* ap = S + (wave * 32 + la) * 136 + kh * 16;
            const char* bp = Bo + la * 136 + kh * 16;
            #pragma unroll
            for (int ks = 0; ks < 4; ks++) {
                s8v a, bf;
                *(long*)&a = *(const long*)ap;
                *((long*)&a + 1) = *(const long*)(ap + 8);
                *(long*)&bf = *(const long*)bp;
                *((long*)&bf + 1) = *(const long*)(bp + 8);
                ap += 32; bp += 32;
                acc = __builtin_amdgcn_mfma_f32_32x32x16_bf16(a, bf, acc, 0, 0, 0);
            }
        }
    }
    __syncthreads();
    // epilogue: C/D layout col=lane&31 (och), row=(r&3)+8*(r>>2)+4*(lane>>5) (px)
    {
        int la = lane & 31, lh = lane >> 5;
        #pragma unroll
        for (int r = 0; r < 16; r++) {
            int pxl = wave * 32 + (r & 3) + 8 * (r >> 2) + 4 * lh;
            E[pxl * 33 + la] = acc[r];
        }
    }
    __syncthreads();
    {
        size_t base = ((size_t)(n * H_ + y) * W_ + xb) * 18;
        #pragma unroll
        for (int k = 0; k < 9; k++) {
            int f = tid + k * 256;
            int pp = f / 18, oc = f % 18;
            off_ws[base + f] = E[pp * 33 + oc] + b_off[oc];
        }
    }
}

// ---------------------------------------------------------------------------
// Bilinear metadata: 4 weights (validity folded) + 4 clamped linear offsets
// ---------------------------------------------------------------------------
__device__ __forceinline__ void bilin_meta(float py, float px,
        float& w00, float& w01, float& w10, float& w11,
        int& o00, int& o01, int& o10, int& o11) {
    float fy0 = floorf(py), fx0 = floorf(px);
    int iy0 = (int)fy0, ix0 = (int)fx0;
    int iy1 = iy0 + 1,  ix1 = ix0 + 1;
    float ly = py - fy0, lx = px - fx0;
    float hy = 1.f - ly, hx = 1.f - lx;
    bool y0ok = (iy0 >= 0) && (iy0 < H_);
    bool y1ok = (iy1 >= 0) && (iy1 < H_);
    bool x0ok = (ix0 >= 0) && (ix0 < W_);
    bool x1ok = (ix1 >= 0) && (ix1 < W_);
    w00 = hy * hx * ((y0ok && x0ok) ? 1.f : 0.f);
    w01 = hy * lx * ((y0ok && x1ok) ? 1.f : 0.f);
    w10 = ly * hx * ((y1ok && x0ok) ? 1.f : 0.f);
    w11 = ly * lx * ((y1ok && x1ok) ? 1.f : 0.f);
    int y0c = min(max(iy0, 0), H_ - 1), y1c = min(max(iy1, 0), H_ - 1);
    int x0c = min(max(ix0, 0), W_ - 1), x1c = min(max(ix1, 0), W_ - 1);
    o00 = y0c * W_ + x0c; o01 = y0c * W_ + x1c;
    o10 = y1c * W_ + x0c; o11 = y1c * W_ + x1c;
}

// ---------------------------------------------------------------------------
// Deformable conv as fused sample+MFMA GEMM: M=128px/block, K=576, N=64.
// Per tap: sample bilinear S[128][64c] bf16 -> LDS; stage W tap [64co][64c];
// 4 waves: each 32px x 64co via 2x v_mfma_f32_32x32x16_bf16 per K-step.
// ---------------------------------------------------------------------------
__global__ __launch_bounds__(256, 4) void k_deform(
        const float* __restrict__ x,
        const float* __restrict__ off_ws,
        const unsigned short* __restrict__ wTb,
        const float* __restrict__ b_def,
        float* __restrict__ out) {
    __shared__ __align__(16) char smem[33792];
    char* Bw = smem;              // [64][68] bf16 = 8704 B
    char* S  = smem + 8704;       // [128][68] bf16 = 17408 B
    float* E = (float*)smem;      // [128][66] f32 = 33792 B (epilogue reuse)

    int tid = threadIdx.x;
    int b = blockIdx.x;
    int n = b & 7;                 // image <-> XCD for L2 locality
    int lidx = b >> 3;
    int y = lidx >> 2;
    int xb = (lidx & 3) << 7;
    int lane = tid & 63, wave = tid >> 6;
    int p = tid & 127, cg = tid >> 7;

    f16v acc0, acc1;
    #pragma unroll
    for (int r = 0; r < 16; r++) { acc0[r] = 0.f; acc1[r] = 0.f; }

    const float* xn = x + (size_t)n * C_ * HW_;
    size_t pix = (size_t)(n * H_ + y) * W_ + xb + p;
    const float2* offp = (const float2*)off_ws + pix * 9;

    for (int t = 0; t < NTAP; t++) {
        __syncthreads();           // S/B readers from prev tap done
        // stage Bw (2048 u32)
        {
            const unsigned* src = (const unsigned*)(wTb + t * CO_ * C_);
            #pragma unroll
            for (int k = 0; k < 8; k++) {
                int s = tid + k * 256;
                int co = s >> 5, q = s & 31;
                *(unsigned*)(Bw + co * 136 + q * 4) = src[s];
            }
        }
        // bilinear meta (once per px per tap; 2x redundant across cg)
        float2 od = offp[t];
        float py = (float)(y + (t / 3) - 1) + od.x;
        float pxf = (float)(xb + p + (t % 3) - 1) + od.y;
        float w00, w01, w10, w11;
        int o00, o01, o10, o11;
        bilin_meta(py, pxf, w00, w01, w10, w11, o00, o01, o10, o11);

        // sample 32 channels: 4 near-coalesced gathers + 4 FMA each
        {
            const float* xc = xn + (size_t)(cg * 32) * HW_;
            char* sp = S + p * 136 + (cg * 32) * 2;
            #pragma unroll 4
            for (int u = 0; u < 16; u++) {
                float v0 = w00 * xc[o00];
                v0 = fmaf(w01, xc[o01], v0);
                v0 = fmaf(w10, xc[o10], v0);
                v0 = fmaf(w11, xc[o11], v0);
                const float* xc1 = xc + HW_;
                float v1 = w00 * xc1[o00];
                v1 = fmaf(w01, xc1[o01], v1);
                v1 = fmaf(w10, xc1[o10], v1);
                v1 = fmaf(w11, xc1[o11], v1);
                *(unsigned*)sp = packbf(v0, v1);
                sp += 4;
                xc += 2 * HW_;
            }
        }
        __syncthreads();
        // MFMA
        {
            int la = lane & 31, kh = lane >> 5;
            const char* ap  = S  + (wave * 32 + la) * 136 + kh * 16;
            const char* b0p = Bw + la * 136 + kh * 16;
            const char* b1p = Bw + (32 + la) * 136 + kh * 16;
            #pragma unroll
            for (int ks = 0; ks < 4; ks++) {
                s8v a, b0, b1;
                *(long*)&a = *(const long*)ap;
                *((long*)&a + 1) = *(const long*)(ap + 8);
                *(long*)&b0 = *(const long*)b0p;
                *((long*)&b0 + 1) = *(const long*)(b0p + 8);
                *(long*)&b1 = *(const long*)b1p;
                *((long*)&b1 + 1) = *(const long*)(b1p + 8);
                ap += 32; b0p += 32; b1p += 32;
                acc0 = __builtin_amdgcn_mfma_f32_32x32x16_bf16(a, b0, acc0, 0, 0, 0);
                acc1 = __builtin_amdgcn_mfma_f32_32x32x16_bf16(a, b1, acc1, 0, 0, 0);
            }
        }
    }
    __syncthreads();
    // acc -> E [px][co]
    {
        int la = lane & 31, lh = lane >> 5;
        #pragma unroll
        for (int r = 0; r < 16; r++) {
            int pxl = wave * 32 + (r & 3) + 8 * (r >> 2) + 4 * lh;
            E[pxl * 66 + la] = acc0[r];
            E[pxl * 66 + 32 + la] = acc1[r];
        }
    }
    __syncthreads();
    // coalesced NCHW store + bias
    {
        int p0 = tid & 63;
        #pragma unroll
        for (int cb = 0; cb < 16; cb++) {
            int co = (cb << 2) + (tid >> 6);
            float bv = b_def[co];
            size_t ob = ((size_t)(n * CO_ + co) * H_ + y) * W_ + xb;
            out[ob + p0]      = E[p0 * 66 + co] + bv;
            out[ob + p0 + 64] = E[(p0 + 64) * 66 + co] + bv;
        }
    }
}

// ---------------------------------------------------------------------------
extern "C" void kernel_launch(void* const* d_in, const int* in_sizes, int n_in,
                              void* d_out, int out_size, void* d_ws, size_t ws_size,
                              hipStream_t stream) {
    const float* x     = (const float*)d_in[0];
    const float* w_off = (const float*)d_in[1];
    const float* b_off = (const float*)d_in[2];
    const float* w_def = (const float*)d_in[3];
    const float* b_def = (const float*)d_in[4];
    float* out = (float*)d_out;

    // ws: wTb bf16 @0 (73728 B), wOb bf16 @80K (36864 B), off_ws @256K (37.7 MB)
    unsigned short* wTb = (unsigned short*)d_ws;
    unsigned short* wOb = (unsigned short*)((char*)d_ws + 80 * 1024);
    float* off_ws       = (float*)((char*)d_ws + 256 * 1024);

    hipLaunchKernelGGL(k_prep_w, dim3(144), dim3(256), 0, stream,
                       w_def, w_off, wTb, wOb);
    hipLaunchKernelGGL(k_off_mfma, dim3(4096), dim3(256), 0, stream,
                       x, wOb, b_off, off_ws);
    hipLaunchKernelGGL(k_deform, dim3(4096), dim3(256), 0, stream,
                       x, off_ws, wTb, b_def, out);
}